// Round 14
// baseline (4532.105 us; speedup 1.0000x reference)
//
#include <hip/hip_runtime.h>
#include <hip/hip_bf16.h>
#include <math.h>

__device__ inline float bf2f(unsigned short u) { return __uint_as_float(((unsigned)u) << 16); }

// ---------------------------------------------------------------------------
// dtype probe: 1 = bf16 inputs, 0 = f32 inputs.
// ---------------------------------------------------------------------------
__global__ void detect_dtype_k(const unsigned short* __restrict__ src, int* __restrict__ flag) {
  int lane = threadIdx.x & 63;
  unsigned short w = src[2 * lane];
  unsigned e = (w >> 7) & 0xFFu;
  bool inr = (e >= 96u && e <= 130u);
  unsigned long long m = __ballot(inr);
  if (lane == 0) *flag = (__popcll(m) >= 48) ? 1 : 0;
}

// ---------------------------------------------------------------------------
// Generic tiled GEMM: f64 accumulate (scalar VALU), f32 STORAGE.
// Numerics bitwise-identical across rounds: LDS stages the raw f32 bit
// pattern (bf16<<16 exact; f32->f64 cvt at use exact); per output element the
// fma chain runs k-ascending (tile/chunk partitioning never reorders it).
// Schedule notes (each is load-bearing):
//  - TWO-barrier single-LDS-buffer per K-step (r4 shape). The 1-barrier dbuf
//    variant (r6) let the compiler pipeline across the barrier: VGPR 56->108,
//    occupancy halved, heavy gemm +16%.
//  - KSTEP 32 (fx64) / 16 (fx32): r12 showed doubling KSTEP is NEUTRAL
//    (283->283 us) — barrier count is not the limiter; reverted to r11 best.
//  - f32 (not f64) LDS staging (r4's f64 staging was LDS-bound).
//  - fx64 MUST stay launch_bounds (256,2): (256,4) caps VGPR at 64 and spills
//    the 32-reg f64 accumulator -> 7 GB/dispatch scratch (r5, 5.4x slower).
//  - B tile stored PERMUTED (col -> (col&15)*RPT + col/16): thread's RPT
//    B-values contiguous -> single ds_read_b128, 2-way bank (free).
//  - k-split staging INTERLEAVED (k0 = t%TPR, stride TPR): kills the 4-way
//    staging-write conflict and keeps adjacent lanes on contiguous global.
//  - r13: fx64 threshold 384 -> 768. The 512-block fx64 dispatches ran at
//    only 2 blocks/CU (grid-limited, Occupancy 32%, VALU idle 27%); route
//    them to fx32 (4x blocks) to A/B occupancy vs instruction-mix.
// ---------------------------------------------------------------------------
struct GemmP {
  const int* dflag;
  const void* A; long long aoff; long long sA; int lda; int tA; int adin;
  const void* B; long long boff; long long sB; int ldb; int tB; int bdin;
  const float* A2; int lda2;
  const void* B2; long long b2off; int ldb2; int K2; int b2din;
  const void* bias;            // d_in bias or null
  const float* add; int ldadd; // f32 add or null (may alias C)
  float* C; long long sC; int ldc;
  int M, Nc, K;
  double scale; int relu;
};

__device__ inline unsigned ldbits(const void* p, long long idx, int dyn, int isdin) {
  if (isdin && dyn) return ((unsigned)((const unsigned short*)p)[idx]) << 16;  // bf16 -> f32 bits (exact)
  return ((const unsigned*)p)[idx];                                            // f32 bits
}

template <int TS, int KS>
__device__ __forceinline__ void gemm_core(const GemmP& p) {
  constexpr int PAD = TS + 4;         // keeps each row 16B-aligned (PAD%4==0)
  constexpr int RPT = TS / 16;        // output elems per thread per dim
  constexpr int TPR = 256 / TS;       // staging threads per tile row
  constexpr int EPT = TS * KS / 256;  // staged elems per thread per operand
  __shared__ __align__(16) float As[KS][PAD];
  __shared__ __align__(16) float Bs[KS][PAD];
  int dyn = p.dflag[0];
  int bz = blockIdx.z;
  // bijective XCD-aware swizzle (per z-slice)
  int gx = gridDim.x;
  int nwg = gx * gridDim.y;
  int lin = blockIdx.y * gx + blockIdx.x;
  int q = nwg >> 3, r = nwg & 7;
  int xcd = lin & 7, cidx = lin >> 3;
  int nl = (xcd < r ? xcd * (q + 1) : r * (q + 1) + (xcd - r) * q) + cidx;
  int by = nl / gx;
  int row0 = by * TS, col0 = (nl - by * gx) * TS;
  int t = threadIdx.x;
  int rg = t >> 4, cg = t & 15;  // rows RPT*rg+i ; cols cg+16*j

  double acc[RPT][RPT];
#pragma unroll
  for (int i = 0; i < RPT; i++)
#pragma unroll
    for (int j = 0; j < RPT; j++) acc[i][j] = 0.0;
  unsigned apf[EPT], bpf[EPT];

  for (int seg = 0; seg < 2; seg++) {
    const void* Ap; const void* Bp;
    long long aofs, bofs;
    int lda, ldb, tA, tB, K, adin, bdin;
    if (seg == 0) {
      Ap = p.A; aofs = p.aoff + (long long)bz * p.sA; lda = p.lda; tA = p.tA; adin = p.adin;
      Bp = p.B; bofs = p.boff + (long long)bz * p.sB; ldb = p.ldb; tB = p.tB; bdin = p.bdin;
      K = p.K;
    } else {
      if (!p.A2) break;
      Ap = p.A2; aofs = 0; lda = p.lda2; tA = 0; adin = 0;
      Bp = p.B2; bofs = p.b2off; ldb = p.ldb2; tB = 0; bdin = p.b2din;
      K = p.K2;
    }
    // staging maps (transpose-aware; k-split always interleaved stride TPR)
    int a_loc = tA ? (t % TS) : (t / TPR);
    int a_k0  = tA ? (t / TS) : (t % TPR);
    int am = row0 + a_loc;
    bool a_ok = am < p.M;
    int b_loc = tB ? (t / TPR) : (t % TS);
    int b_k0  = tB ? (t % TPR) : (t / TS);
    int bn = col0 + b_loc;
    bool b_ok = bn < p.Nc;
    int b_pos = (b_loc & 15) * RPT + (b_loc >> 4);  // permuted B column slot
    // incremental offsets: elem u of step ts sits at base + ts*step + u*ustride
    long long abase = aofs + (tA ? (long long)a_k0 * lda + am : (long long)am * lda + a_k0);
    long long austr = tA ? (long long)TPR * lda : TPR;
    long long astep = tA ? (long long)KS * lda : KS;
    long long bbase = bofs + (tB ? (long long)bn * ldb + b_k0 : (long long)b_k0 * ldb + bn);
    long long bustr = tB ? TPR : (long long)TPR * ldb;
    long long bstep = tB ? KS : (long long)KS * ldb;

    auto LOAD = [&](int k0) {
#pragma unroll
      for (int u = 0; u < EPT; u++) {
        int k = k0 + a_k0 + u * TPR;
        apf[u] = (a_ok && k < K) ? ldbits(Ap, abase + u * austr, dyn, adin) : 0u;
      }
#pragma unroll
      for (int u = 0; u < EPT; u++) {
        int k = k0 + b_k0 + u * TPR;
        bpf[u] = (b_ok && k < K) ? ldbits(Bp, bbase + u * bustr, dyn, bdin) : 0u;
      }
      abase += astep; bbase += bstep;
    };
    auto STORE = [&]() {
#pragma unroll
      for (int u = 0; u < EPT; u++) As[a_k0 + u * TPR][a_loc] = __uint_as_float(apf[u]);
#pragma unroll
      for (int u = 0; u < EPT; u++) Bs[b_k0 + u * TPR][b_pos] = __uint_as_float(bpf[u]);
    };
    int nst = (K + KS - 1) / KS;
    LOAD(0);
    for (int ts = 0; ts < nst; ts++) {
      __syncthreads();  // previous step's compute done; LDS free
      STORE();          // prefetch regs die here -> low VGPR
      __syncthreads();  // LDS ready
      if (ts + 1 < nst) LOAD((ts + 1) * KS);  // global prefetch overlaps compute
#pragma unroll
      for (int kk = 0; kk < KS; kk++) {
        double av[RPT], bv[RPT];
#pragma unroll
        for (int i = 0; i < RPT; i++) av[i] = (double)As[kk][RPT * rg + i];  // 1x b128, broadcast
#pragma unroll
        for (int j = 0; j < RPT; j++) bv[j] = (double)Bs[kk][RPT * cg + j];  // 1x b128, 2-way (free)
#pragma unroll
        for (int i = 0; i < RPT; i++)
#pragma unroll
          for (int j = 0; j < RPT; j++) acc[i][j] = fma(av[i], bv[j], acc[i][j]);
      }
    }
  }
  const float* addb = p.add;
  float* Cb = p.C + (long long)bz * p.sC;
#pragma unroll
  for (int i = 0; i < RPT; i++) {
    int m = row0 + RPT * rg + i;
    if (m >= p.M) continue;
#pragma unroll
    for (int j = 0; j < RPT; j++) {
      int n = col0 + cg + 16 * j;   // bv[j] holds col cg+16j: p(cg+16j)=RPT*cg+j
      if (n >= p.Nc) continue;
      double v = acc[i][j] * p.scale;
      if (p.bias)
        v += dyn ? (double)bf2f(((const unsigned short*)p.bias)[n])
                 : (double)((const float*)p.bias)[n];
      if (addb) v += (double)addb[(long long)m * p.ldadd + n];
      if (p.relu) v = fmax(v, 0.0);
      Cb[(long long)m * p.ldc + n] = (float)v;  // f32 storage rounding
    }
  }
}

__launch_bounds__(256, 4)
__global__ void gemm_fx32(GemmP p) { gemm_core<32, 16>(p); }

// (256,2): 128-VGPR budget. DO NOT tighten to (256,4) — 64-VGPR cap spills
// the 32-reg f64 accumulator (r5: 7 GB/dispatch scratch, 5.4x slower).
__launch_bounds__(256, 2)
__global__ void gemm_fx64(GemmP p) { gemm_core<64, 32>(p); }

// ---------------------------------------------------------------------------
// Row softmax in-place: f32 storage, f64 internal
// ---------------------------------------------------------------------------
__launch_bounds__(256)
__global__ void row_softmax_k(float* __restrict__ A, int N) {
  long long row = (long long)blockIdx.x * 4 + (threadIdx.x >> 6);
  int lane = threadIdx.x & 63;
  float* a = A + row * N;
  double ev[8];
  int nc = N >> 6;
  double mx = -INFINITY;
  for (int k = 0; k < nc; k++) mx = fmax(mx, (double)a[lane + (k << 6)]);
  for (int off = 32; off; off >>= 1) mx = fmax(mx, __shfl_xor(mx, off, 64));
  double s = 0.0;
  for (int k = 0; k < nc; k++) { double e = exp((double)a[lane + (k << 6)] - mx); ev[k] = e; s += e; }
  for (int off = 32; off; off >>= 1) s += __shfl_xor(s, off, 64);
  double inv = 1.0 / s;
  for (int k = 0; k < nc; k++) a[lane + (k << 6)] = (float)(ev[k] * inv);
}

// ---------------------------------------------------------------------------
// Ms = 0.5*(Aff + Aff^T) -> f32
// ---------------------------------------------------------------------------
__launch_bounds__(256)
__global__ void msym_k(const void* __restrict__ Aff, float* __restrict__ Ms, int d,
                       const int* __restrict__ dflag) {
  int fl = dflag[0];
  int idx = blockIdx.x * 256 + threadIdx.x;
  if (idx < d * d) {
    int i = idx / d, j = idx - i * d;
    double a, b;
    if (fl) {
      a = (double)bf2f(((const unsigned short*)Aff)[idx]);
      b = (double)bf2f(((const unsigned short*)Aff)[j * d + i]);
    } else {
      a = (double)((const float*)Aff)[idx];
      b = (double)((const float*)Aff)[j * d + i];
    }
    Ms[idx] = (float)(0.5 * (a + b));
  }
}

// ---------------------------------------------------------------------------
// Sinkhorn (padded RPM), log-domain fixed point: S f32, u/v f64, P f32.
// ---------------------------------------------------------------------------
__launch_bounds__(256)
__global__ void sink_u_k(const float* __restrict__ S, const double* __restrict__ V,
                         double* __restrict__ U, int N) {
  extern __shared__ double vsh[];
  int b = blockIdx.y;
  const float* Sb = S + (long long)b * N * N;
  const double* Vb = V + (long long)b * N;
  int tid = threadIdx.x, lane = tid & 63, wv = tid >> 6;
  for (int c = tid; c < N; c += 256) vsh[c] = Vb[c];
  __syncthreads();
  int row = blockIdx.x * 4 + wv;
  const float* Sr = Sb + (long long)row * N;
  double m = (lane == 0) ? 0.0 : -INFINITY;
  double s = (lane == 0) ? 1.0 : 0.0;
  for (int c = lane; c < N; c += 64) {
    double x = (double)Sr[c] - vsh[c];
    if (x > m) { s = s * exp(m - x) + 1.0; m = x; }
    else s += exp(x - m);
  }
  for (int off = 32; off; off >>= 1) {
    double mo = __shfl_xor(m, off, 64);
    double so = __shfl_xor(s, off, 64);
    double mm = fmax(m, mo);
    s = s * exp(m - mm) + so * exp(mo - mm);
    m = mm;
  }
  if (lane == 0) U[(long long)b * N + row] = m + log(s);
}

// 16 columns x 16 row-groups per block: grid (N/16, pc)
__launch_bounds__(256)
__global__ void sink_v_k(const float* __restrict__ S, const double* __restrict__ U,
                         double* __restrict__ V, int N) {
  extern __shared__ double ush[];
  double* mred = ush + N;
  double* sred = mred + 256;
  int b = blockIdx.y;
  const float* Sb = S + (long long)b * N * N;
  int tid = threadIdx.x, cl = tid & 15, rg = tid >> 4;
  int c = blockIdx.x * 16 + cl;
  for (int i = tid; i < N; i += 256) ush[i] = U[(long long)b * N + i];
  __syncthreads();
  double m = (rg == 0) ? 0.0 : -INFINITY;
  double s = (rg == 0) ? 1.0 : 0.0;
  for (int i = rg; i < N; i += 16) {
    double x = (double)Sb[(long long)i * N + c] - ush[i];
    if (x > m) { s = s * exp(m - x) + 1.0; m = x; }
    else s += exp(x - m);
  }
  mred[rg * 16 + cl] = m; sred[rg * 16 + cl] = s;
  __syncthreads();
  if (rg == 0) {
    for (int g = 1; g < 16; g++) {
      double mo = mred[g * 16 + cl], so = sred[g * 16 + cl];
      double mm = fmax(m, mo);
      s = s * exp(m - mm) + so * exp(mo - mm);
      m = mm;
    }
    V[(long long)b * N + c] = m + log(s);
  }
}

__launch_bounds__(256)
__global__ void sink_p_k(const float* __restrict__ S, const double* __restrict__ U,
                         const double* __restrict__ V, float* __restrict__ P, int N) {
  int b = blockIdx.y;
  long long base = (long long)b * N * N;
  const double* Ub = U + (long long)b * N;
  const double* Vb = V + (long long)b * N;
  for (long long e = (long long)blockIdx.x * 256 + threadIdx.x; e < (long long)N * N;
       e += (long long)gridDim.x * 256) {
    int i = (int)(e / N), j = (int)(e - (long long)i * N);
    P[base + e] = (float)exp((double)S[base + e] - Ub[i] - Vb[j]);  // f32 storage
  }
}

// ---------------------------------------------------------------------------
// Top-k pooling: f64 math on f32-stored emb; FINAL SCORE ROUNDED TO F32
// ---------------------------------------------------------------------------
__launch_bounds__(256)
__global__ void colstats_k(const float* __restrict__ emb, double* __restrict__ stats, int N, int d) {
  int g = blockIdx.y;
  int cl = threadIdx.x & 63;
  int c = blockIdx.x * 64 + cl;
  int rg = threadIdx.x >> 6;
  const float* e = emb + (long long)g * N * d;
  __shared__ double redm[4][64];
  __shared__ double reds[4][64];
  double mx = -INFINITY;
  for (int r = rg; r < N; r += 4) mx = fmax(mx, (double)e[(long long)r * d + c]);
  redm[rg][cl] = mx;
  __syncthreads();
  mx = fmax(fmax(redm[0][cl], redm[1][cl]), fmax(redm[2][cl], redm[3][cl]));
  __syncthreads();
  double s = 0.0;
  for (int r = rg; r < N; r += 4) s += exp((double)e[(long long)r * d + c] - mx);
  reds[rg][cl] = s;
  __syncthreads();
  if (rg == 0) {
    s = reds[0][cl] + reds[1][cl] + reds[2][cl] + reds[3][cl];
    stats[((long long)g * d + c) * 2] = mx;
    stats[((long long)g * d + c) * 2 + 1] = 1.0 / s;
  }
}

__launch_bounds__(256)
__global__ void score_k(const float* __restrict__ emb, const double* __restrict__ stats,
                        double* __restrict__ score, int N, int d) {
  int g = blockIdx.y;
  int r = blockIdx.x * 64 + (threadIdx.x >> 2);
  int sub = threadIdx.x & 3;
  const float* e = emb + ((long long)g * N + r) * d;
  const double* st = stats + (long long)g * d * 2;
  double s = 0.0;
  for (int c = sub; c < d; c += 4) s += exp((double)e[c] - st[2 * c]) * st[2 * c + 1];
  s += __shfl_down(s, 2, 4);
  s += __shfl_down(s, 1, 4);
  if (sub == 0) score[(long long)g * N + r] = (double)(float)s;  // f32 rounding
}

__launch_bounds__(256)
__global__ void topk_sort_k(const double* __restrict__ score, int* __restrict__ SIDX,
                            int N, int k) {
  __shared__ double sv[1024];
  __shared__ int si[1024];
  int g = blockIdx.x, tid = threadIdx.x;
  (void)k;
  for (int i = tid; i < N; i += 256) { sv[i] = score[(long long)g * N + i]; si[i] = i; }
  __syncthreads();
  for (int kk = 2; kk <= N; kk <<= 1) {
    for (int j = kk >> 1; j > 0; j >>= 1) {
      for (int i = tid; i < N; i += 256) {
        int ixj = i ^ j;
        if (ixj > i) {
          double v1 = sv[i], v2 = sv[ixj];
          int x1 = si[i], x2 = si[ixj];
          bool gtr = (v1 < v2) || (v1 == v2 && x1 > x2);
          bool up = ((i & kk) == 0);
          if (gtr == up) { sv[i] = v2; sv[ixj] = v1; si[i] = x2; si[ixj] = x1; }
        }
      }
      __syncthreads();
    }
  }
  for (int i = tid; i < N; i += 256) SIDX[(long long)g * N + i] = si[i];
}

// grid-stride gather over (chunk, g): r7 profile showed the old <<<s>>> launch
// (8 blocks) at 310 us/dispatch, 0.35% occupancy — pure grid starvation.
// k*d <= 131072 fits int; row/col walked incrementally (no div in loop).
__launch_bounds__(256)
__global__ void gather_k(const int* __restrict__ SIDX, const float* __restrict__ emb,
                         float* __restrict__ out, int N, int d, int k) {
  int g = blockIdx.y;
  int total = k * d;
  const int* sx = SIDX + (long long)g * N;
  const float* eb = emb + (long long)g * N * d;
  float* ob = out + (long long)g * total;
  int stride = gridDim.x * 256;
  int e0 = blockIdx.x * 256 + threadIdx.x;
  int r = e0 / d, c = e0 - r * d;
  int rs = stride / d, cs = stride - rs * d;  // per-step row/col increments
  for (int e = e0; e < total; e += stride) {
    ob[e] = eb[(long long)sx[r] * d + c];
    r += rs; c += cs;
    if (c >= d) { c -= d; r += 1; }
  }
}

// output converter: f32 -> bf16/f32 per flag
__launch_bounds__(256)
__global__ void cvt_out_k(const float* __restrict__ src, void* __restrict__ dst,
                          long long oofs, int n, const int* __restrict__ dflag) {
  int fl = dflag[0];
  int i = blockIdx.x * 256 + threadIdx.x;
  if (i < n) {
    float v = src[i];
    if (fl) ((__hip_bfloat16*)dst)[oofs + i] = __float2bfloat16(v);
    else ((float*)dst)[oofs + i] = v;
  }
}

// ---------------------------------------------------------------------------
// Host orchestration — f32 arena, ws_size-adaptive pair batching.
// ---------------------------------------------------------------------------
extern "C" void kernel_launch(void* const* d_in, const int* in_sizes, int n_in,
                              void* d_out, int out_size, void* d_ws, size_t ws_size,
                              hipStream_t stream) {
  (void)in_sizes; (void)n_in; (void)out_size;
  static const int NL[3] = {1024, 512, 256};
  static const int DL[3] = {512, 256, 128};
  static const int DINL[3] = {3, 512, 256};
  static const int IWp[3]={0,11,23}, IBp[3]={1,12,24}, IWe[3]={2,13,25}, IBe[3]={3,14,26};
  static const int IWt[3]={-1,15,27};
  static const int IWa[3]={4,16,28}, IBa[3]={5,17,29}, IWu[3]={6,18,30}, IBu[3]={7,19,31};
  static const int IAff[3]={8,20,32}, IWc[3]={9,21,33}, IBc[3]={10,22,34};

  auto Wv = [&](int t) { return (const void*)d_in[4 + t]; };

  float* ws = (float*)d_ws;
  const long long PER_PC = 5257232LL;  // floats per pair
  int pc = 1;
  if (ws_size >= (size_t)(PER_PC * 4 * 4 + 64)) pc = 4;
  else if (ws_size >= (size_t)(PER_PC * 2 * 4 + 64)) pc = 2;

  float* A0 = ws;
  float* B0 = A0 + 2097152LL * pc;
  float* C0 = B0 + 1048576LL * pc;
  float* D0 = C0 + 1048576LL * pc;
  float* IN = D0 + 524288LL * pc;
  double* ST = (double*)(IN + 524288LL * pc);  // 2048*pc doubles
  double* SC = ST + 2048LL * pc;               // 2048*pc doubles
  double* SU = SC + 2048LL * pc;               // 1024*pc doubles
  double* SV = SU + 1024LL * pc;               // 1024*pc doubles
  int* SIDX = (int*)(SV + 1024LL * pc);        // 2048*pc ints
  int* FLAG = SIDX + 2048LL * pc;

  detect_dtype_k<<<dim3(1), dim3(64), 0, stream>>>((const unsigned short*)d_in[0], FLAG);

  GemmP p_;
  auto gemm = [&](const void* A, long long aoff, long long sA, int lda, int tA, int adin,
                  const void* B, long long boff, long long sB, int ldb, int tB, int bdin,
                  const float* A2, int lda2,
                  const void* B2, long long b2off, int ldb2, int K2, int b2din,
                  const void* bias, const float* add, int ldadd,
                  float* C, long long sC, int ldc, int M, int Nc, int K,
                  double scale, int relu, int batches) {
    p_.dflag = FLAG;
    p_.A = A; p_.aoff = aoff; p_.sA = sA; p_.lda = lda; p_.tA = tA; p_.adin = adin;
    p_.B = B; p_.boff = boff; p_.sB = sB; p_.ldb = ldb; p_.tB = tB; p_.bdin = bdin;
    p_.A2 = A2; p_.lda2 = lda2;
    p_.B2 = B2; p_.b2off = b2off; p_.ldb2 = ldb2; p_.K2 = K2; p_.b2din = b2din;
    p_.bias = bias; p_.add = add; p_.ldadd = ldadd;
    p_.C = C; p_.sC = sC; p_.ldc = ldc; p_.M = M; p_.Nc = Nc; p_.K = K;
    p_.scale = scale; p_.relu = relu;
    long long b64 = (long long)((Nc + 63) / 64) * ((M + 63) / 64) * batches;
    if (b64 >= 768) {
      dim3 grid((Nc + 63) / 64, (M + 63) / 64, batches);
      gemm_fx64<<<grid, dim3(256), 0, stream>>>(p_);
    } else {
      dim3 grid((Nc + 31) / 32, (M + 31) / 32, batches);
      gemm_fx32<<<grid, dim3(256), 0, stream>>>(p_);
    }
  };

  for (int p0 = 0; p0 < 4; p0 += pc) {
    const int s = 2 * pc;
    for (int L = 0; L < 3; L++) {
      int N = NL[L], d = DL[L], din = DINL[L];
      long long ns = (long long)N * d, NN = (long long)N * N;
      int sN = s * N, pcN = pc * N;
      float* X2 = A0;
      float* H = B0;
      float* X3 = C0;
      float* Af = D0;
      float* Spt = A0;
      float* Ppt = A0 + (long long)pc * NN;
      float* G = B0;
      float* MSp = B0 + (long long)pc * ns;
      float* Y = B0;
      float* EMB = A0;

      if (L == 0) {
        long long poff = (long long)p0 * N * 3;
        float* X2t = X2 + (long long)pcN * 2 * d;
        gemm(d_in[0],poff,0,3,0,1, Wv(IWp[0]),0,0,d,0,1, nullptr,0, nullptr,0,0,0,0,
             Wv(IBp[0]), nullptr,0, X2, 0, 2*d, pcN, d, 3, 1.0, 1, 1);
        gemm(d_in[0],poff,0,3,0,1, Wv(IWe[0]),0,0,d,0,1, nullptr,0, nullptr,0,0,0,0,
             Wv(IBe[0]), nullptr,0, X2 + d, 0, 2*d, pcN, d, 3, 1.0, 1, 1);
        gemm(d_in[1],poff,0,3,0,1, Wv(IWp[0]),0,0,d,0,1, nullptr,0, nullptr,0,0,0,0,
             Wv(IBp[0]), nullptr,0, X2t, 0, 2*d, pcN, d, 3, 1.0, 1, 1);
        gemm(d_in[1],poff,0,3,0,1, Wv(IWe[0]),0,0,d,0,1, nullptr,0, nullptr,0,0,0,0,
             Wv(IBe[0]), nullptr,0, X2t + d, 0, 2*d, pcN, d, 3, 1.0, 1, 1);
      } else {
        gemm(IN,0,0,din,0,0, Wv(IWp[L]),0,0,d,0,1, nullptr,0, nullptr,0,0,0,0,
             Wv(IBp[L]), nullptr,0, X2, 0, 2*d, sN, d, din, 1.0, 1, 1);
        gemm(IN,0,0,din,0,0, Wv(IWe[L]),0,0,d,0,1, nullptr,0, nullptr,0,0,0,0,
             Wv(IBe[L]), nullptr,0, X2 + d, 0, 2*d, sN, d, din, 1.0, 1, 1);
      }
      if (L > 0) {
        float* SE = B0;
        double inv = (double)(float)(1.0 / sqrt((double)d));  // np.float32 constant
        gemm(X2,0,0,2*d,0,0, Wv(IWt[L]),0,0,d,0,1, nullptr,0, nullptr,0,0,0,0,
             nullptr, nullptr,0, SE, 0, d, sN, d, 2*d, 1.0, 0, 1);
        gemm(SE,0,ns,d,0,0, SE,0,ns,d,1,0, nullptr,0, nullptr,0,0,0,0,
             nullptr, nullptr,0, Af, NN, N, N, N, d, inv, 0, s);
        row_softmax_k<<<dim3(sN / 4), dim3(256), 0, stream>>>(Af, N);
      }
      gemm(X2,0,0,2*d,0,0, Wv(IWa[L]),0,0,d,0,1, nullptr,0, nullptr,0,0,0,0,
           Wv(IBa[L]), nullptr,0, H, 0, d, sN, d, 2*d, 1.0, 0, 1);
      if (L == 0) {
        gemm(d_in[2],(long long)p0*NN,NN,N,0,1, H,0,ns,d,0,0, nullptr,0, nullptr,0,0,0,0,
             nullptr, nullptr,0, X3, ns, d, N, d, N, 1.0, 0, pc);
        gemm(d_in[3],(long long)p0*NN,NN,N,0,1, H + (long long)pc*ns,0,ns,d,0,0, nullptr,0, nullptr,0,0,0,0,
             nullptr, nullptr,0, X3 + (long long)pc*ns, ns, d, N, d, N, 1.0, 0, pc);
      } else {
        gemm(Af,0,NN,N,0,0, H,0,ns,d,0,0, nullptr,0, nullptr,0,0,0,0,
             nullptr, nullptr,0, X3, ns, d, N, d, N, 1.0, 0, s);
      }
      gemm(X2,0,0,2*d,0,0, Wv(IWu[L]),0,0,d,0,1, nullptr,0, nullptr,0,0,0,0,
           Wv(IBu[L]), X3,d, X3, 0, d, sN, d, 2*d, 1.0, 1, 1);
      msym_k<<<dim3((d * d + 255) / 256), dim3(256), 0, stream>>>(Wv(IAff[L]), MSp, d, FLAG);
      gemm(X3 + (long long)pc*ns,0,0,d,0,0, MSp,0,0,d,0,0, nullptr,0, nullptr,0,0,0,0,
           nullptr, nullptr,0, G, 0, d, pcN, d, d, 1.0, 0, 1);
      gemm(X3,0,ns,d,0,0, G,0,ns,d,1,0, nullptr,0, nullptr,0,0,0,0,
           nullptr, nullptr,0, Spt, NN, N, N, N, d, 1.0, 0, pc);
      hipMemsetAsync(SV, 0, (size_t)pc * N * sizeof(double), stream);
      for (int it = 0; it < 20; it++) {
        sink_u_k<<<dim3(N / 4, pc), dim3(256), N * sizeof(double), stream>>>(Spt, SV, SU, N);
        sink_v_k<<<dim3(N / 16, pc), dim3(256), (N + 512) * sizeof(double), stream>>>(Spt, SU, SV, N);
      }
      sink_p_k<<<dim3(256, pc), dim3(256), 0, stream>>>(Spt, SU, SV, Ppt, N);
      if (L == 2) {
        int on = pc * 65536;
        cvt_out_k<<<dim3((on + 255) / 256), dim3(256), 0, stream>>>(
            Ppt, d_out, (long long)p0 * 65536, on, FLAG);
      } else {
        gemm(Ppt,0,NN,N,0,0, X3 + (long long)pc*ns,0,ns,d,0,0, nullptr,0, nullptr,0,0,0,0,
             nullptr, nullptr,0, Y, ns, d, N, d, N, 1.0, 0, pc);
        gemm(Ppt,0,NN,N,1,0, X3,0,ns,d,0,0, nullptr,0, nullptr,0,0,0,0,
             nullptr, nullptr,0, Y + (long long)pc*ns, ns, d, N, d, N, 1.0, 0, pc);
        gemm(X3,0,0,d,0,0, Wv(IWc[L]),0,0,d,0,1, Y,d, Wv(IWc[L]),(long long)d*d,d,d,1,
             Wv(IBc[L]), nullptr,0, EMB, 0, d, sN, d, d, 1.0, 0, 1);
        colstats_k<<<dim3(d / 64, s), dim3(256), 0, stream>>>(EMB, ST, N, d);
        score_k<<<dim3(N / 64, s), dim3(256), 0, stream>>>(EMB, ST, SC, N, d);
        topk_sort_k<<<dim3(s), dim3(256), 0, stream>>>(SC, SIDX, N, N / 2);
        gather_k<<<dim3(128, s), dim3(256), 0, stream>>>(SIDX, EMB, IN, N, d, N / 2);
      }
    }
  }
}

// Round 15
// 4060.575 us; speedup vs baseline: 1.1161x; 1.1161x over previous
//
#include <hip/hip_runtime.h>
#include <hip/hip_bf16.h>
#include <math.h>

__device__ inline float bf2f(unsigned short u) { return __uint_as_float(((unsigned)u) << 16); }

typedef double f64x4 __attribute__((ext_vector_type(4)));

// Decoded MFMA f64 layout tables (r2-verified machinery):
// [0..255]   rowtab[lane*4+v] : D row label (0..15) of acc elem v
// [256..511] coltab[lane*4+v] : D col label
// [512..515] invsig[kg]       : B k-group feed correction
// [516]      ok               : 1 = MFMA path verified, else scalar fallback
__device__ int g_tab[520];

// ---------------------------------------------------------------------------
// MFMA f64 16x16x4 layout probe + end-to-end integer verification (1 wave).
// r2 ran this exact probe: decoded, verified, and the full MFMA bench PASSED
// with absmax identical to scalar (1.525879e-05) -> numerics safe.
// ---------------------------------------------------------------------------
__global__ void mfma_probe_k() {
  int l = threadIdx.x;
  if (l >= 64) return;
  double p4[16];
  p4[0] = 1.0;
  for (int i = 1; i < 16; i++) p4[i] = p4[i - 1] * 4.0;
  f64x4 z; z[0] = 0.0; z[1] = 0.0; z[2] = 0.0; z[3] = 0.0;
  int ok = 1;
  int ln = l & 15, kg = l >> 4;
  f64x4 d1 = __builtin_amdgcn_mfma_f64_16x16x4f64(p4[ln], 1.0, z, 0, 0, 0);
  f64x4 d2 = __builtin_amdgcn_mfma_f64_16x16x4f64(1.0, p4[ln], z, 0, 0, 0);
  int sig[4];
  for (int t = 0; t < 4; t++) {
    f64x4 dt = __builtin_amdgcn_mfma_f64_16x16x4f64((kg == t) ? 1.0 : 0.0, p4[kg], z, 0, 0, 0);
    int e = -1;
    for (int i = 0; i < 4; i++)
      if (dt[0] == p4[i]) e = i;
    if (e < 0) ok = 0;
    sig[t] = (e < 0) ? t : e;
  }
  int invs[4] = {0, 1, 2, 3};
  for (int t = 0; t < 4; t++) invs[sig[t]] = t;
  int rt[4], ct[4];
  for (int v = 0; v < 4; v++) {
    int ri = -1, ci = -1;
    for (int i = 0; i < 16; i++) {
      if (d1[v] == 4.0 * p4[i]) ri = i;
      if (d2[v] == 4.0 * p4[i]) ci = i;
    }
    if (ri < 0 || ci < 0) ok = 0;
    rt[v] = (ri < 0) ? 0 : ri;
    ct[v] = (ci < 0) ? 0 : ci;
  }
  double av = (double)(((ln * 3 + kg * 5) % 7) - 3);
  double bv = (double)(((invs[kg] * 11 + ln * 2) % 5) - 2);
  f64x4 dd = __builtin_amdgcn_mfma_f64_16x16x4f64(av, bv, z, 0, 0, 0);
  for (int v = 0; v < 4; v++) {
    int i = rt[v], j = ct[v];
    double ex = 0.0;
    for (int k = 0; k < 4; k++)
      ex += (double)(((i * 3 + k * 5) % 7) - 3) * (double)(((k * 11 + j * 2) % 5) - 2);
    if (dd[v] != ex) ok = 0;
  }
  unsigned long long allok = __ballot(ok != 0);
  for (int v = 0; v < 4; v++) {
    g_tab[l * 4 + v] = rt[v];
    g_tab[256 + l * 4 + v] = ct[v];
  }
  if (l < 4) g_tab[512 + l] = invs[l];
  if (l == 0) g_tab[516] = (allok == ~0ULL) ? 1 : 0;
}

// ---------------------------------------------------------------------------
// dtype probe: 1 = bf16 inputs, 0 = f32 inputs.
// ---------------------------------------------------------------------------
__global__ void detect_dtype_k(const unsigned short* __restrict__ src, int* __restrict__ flag) {
  int lane = threadIdx.x & 63;
  unsigned short w = src[2 * lane];
  unsigned e = (w >> 7) & 0xFFu;
  bool inr = (e >= 96u && e <= 130u);
  unsigned long long m = __ballot(inr);
  if (lane == 0) *flag = (__popcll(m) >= 48) ? 1 : 0;
}

// ---------------------------------------------------------------------------
// GEMM params. f64 accumulate, f32 storage. Staging: raw f32 bit pattern in
// LDS (bf16<<16 exact; f32->f64 cvt exact).
// ---------------------------------------------------------------------------
struct GemmP {
  const int* dflag;
  const void* A; long long aoff; long long sA; int lda; int tA; int adin;
  const void* B; long long boff; long long sB; int ldb; int tB; int bdin;
  const float* A2; int lda2;
  const void* B2; long long b2off; int ldb2; int K2; int b2din;
  const void* bias;            // d_in bias or null
  const float* add; int ldadd; // f32 add or null (may alias C)
  float* C; long long sC; int ldc;
  int M, Nc, K;
  double scale; int relu;
};

__device__ inline unsigned ldbits(const void* p, long long idx, int dyn, int isdin) {
  if (isdin && dyn) return ((unsigned)((const unsigned short*)p)[idx]) << 16;
  return ((const unsigned*)p)[idx];
}

// ---------------------------------------------------------------------------
// fx32: scalar core, 32-tile, permuted-B b128 reads (r11-verified).
// ---------------------------------------------------------------------------
template <int TS, int KS>
__device__ __forceinline__ void gemm_core(const GemmP& p) {
  constexpr int PAD = TS + 4;
  constexpr int RPT = TS / 16;
  constexpr int TPR = 256 / TS;
  constexpr int EPT = TS * KS / 256;
  __shared__ __align__(16) float As[KS][PAD];
  __shared__ __align__(16) float Bs[KS][PAD];
  int dyn = p.dflag[0];
  int bz = blockIdx.z;
  int gx = gridDim.x;
  int nwg = gx * gridDim.y;
  int lin = blockIdx.y * gx + blockIdx.x;
  int q = nwg >> 3, r = nwg & 7;
  int xcd = lin & 7, cidx = lin >> 3;
  int nl = (xcd < r ? xcd * (q + 1) : r * (q + 1) + (xcd - r) * q) + cidx;
  int by = nl / gx;
  int row0 = by * TS, col0 = (nl - by * gx) * TS;
  int t = threadIdx.x;
  int rg = t >> 4, cg = t & 15;

  double acc[RPT][RPT];
#pragma unroll
  for (int i = 0; i < RPT; i++)
#pragma unroll
    for (int j = 0; j < RPT; j++) acc[i][j] = 0.0;
  unsigned apf[EPT], bpf[EPT];

  for (int seg = 0; seg < 2; seg++) {
    const void* Ap; const void* Bp;
    long long aofs, bofs;
    int lda, ldb, tA, tB, K, adin, bdin;
    if (seg == 0) {
      Ap = p.A; aofs = p.aoff + (long long)bz * p.sA; lda = p.lda; tA = p.tA; adin = p.adin;
      Bp = p.B; bofs = p.boff + (long long)bz * p.sB; ldb = p.ldb; tB = p.tB; bdin = p.bdin;
      K = p.K;
    } else {
      if (!p.A2) break;
      Ap = p.A2; aofs = 0; lda = p.lda2; tA = 0; adin = 0;
      Bp = p.B2; bofs = p.b2off; ldb = p.ldb2; tB = 0; bdin = p.b2din;
      K = p.K2;
    }
    int a_loc = tA ? (t % TS) : (t / TPR);
    int a_k0  = tA ? (t / TS) : (t % TPR);
    int am = row0 + a_loc;
    bool a_ok = am < p.M;
    int b_loc = tB ? (t / TPR) : (t % TS);
    int b_k0  = tB ? (t % TPR) : (t / TS);
    int bn = col0 + b_loc;
    bool b_ok = bn < p.Nc;
    int b_pos = (b_loc & 15) * RPT + (b_loc >> 4);  // permuted slot
    long long abase = aofs + (tA ? (long long)a_k0 * lda + am : (long long)am * lda + a_k0);
    long long austr = tA ? (long long)TPR * lda : TPR;
    long long astep = tA ? (long long)KS * lda : KS;
    long long bbase = bofs + (tB ? (long long)bn * ldb + b_k0 : (long long)b_k0 * ldb + bn);
    long long bustr = tB ? TPR : (long long)TPR * ldb;
    long long bstep = tB ? KS : (long long)KS * ldb;

    auto LOAD = [&](int k0) {
#pragma unroll
      for (int u = 0; u < EPT; u++) {
        int k = k0 + a_k0 + u * TPR;
        apf[u] = (a_ok && k < K) ? ldbits(Ap, abase + u * austr, dyn, adin) : 0u;
      }
#pragma unroll
      for (int u = 0; u < EPT; u++) {
        int k = k0 + b_k0 + u * TPR;
        bpf[u] = (b_ok && k < K) ? ldbits(Bp, bbase + u * bustr, dyn, bdin) : 0u;
      }
      abase += astep; bbase += bstep;
    };
    auto STORE = [&]() {
#pragma unroll
      for (int u = 0; u < EPT; u++) As[a_k0 + u * TPR][a_loc] = __uint_as_float(apf[u]);
#pragma unroll
      for (int u = 0; u < EPT; u++) Bs[b_k0 + u * TPR][b_pos] = __uint_as_float(bpf[u]);
    };
    int nst = (K + KS - 1) / KS;
    LOAD(0);
    for (int ts = 0; ts < nst; ts++) {
      __syncthreads();
      STORE();
      __syncthreads();
      if (ts + 1 < nst) LOAD((ts + 1) * KS);
#pragma unroll
      for (int kk = 0; kk < KS; kk++) {
        double av[RPT], bv[RPT];
#pragma unroll
        for (int i = 0; i < RPT; i++) av[i] = (double)As[kk][RPT * rg + i];
#pragma unroll
        for (int j = 0; j < RPT; j++) bv[j] = (double)Bs[kk][RPT * cg + j];
#pragma unroll
        for (int i = 0; i < RPT; i++)
#pragma unroll
          for (int j = 0; j < RPT; j++) acc[i][j] = fma(av[i], bv[j], acc[i][j]);
      }
    }
  }
  const float* addb = p.add;
  float* Cb = p.C + (long long)bz * p.sC;
#pragma unroll
  for (int i = 0; i < RPT; i++) {
    int m = row0 + RPT * rg + i;
    if (m >= p.M) continue;
#pragma unroll
    for (int j = 0; j < RPT; j++) {
      int n = col0 + cg + 16 * j;
      if (n >= p.Nc) continue;
      double v = acc[i][j] * p.scale;
      if (p.bias)
        v += dyn ? (double)bf2f(((const unsigned short*)p.bias)[n])
                 : (double)((const float*)p.bias)[n];
      if (addb) v += (double)addb[(long long)m * p.ldadd + n];
      if (p.relu) v = fmax(v, 0.0);
      Cb[(long long)m * p.ldc + n] = (float)v;
    }
  }
}

__launch_bounds__(256, 4)
__global__ void gemm_fx32(GemmP p) { gemm_core<32, 16>(p); }

// ---------------------------------------------------------------------------
// fx64: MFMA f64 core. 64-tile, KS=32, 4 waves each owning a 32x32 quadrant.
// r11 staging (f32 bits, interleaved k-split, coalesced) with UNPERMUTED B.
// Per 4-k group per lane: 4 b32 LDS reads + 4 cvt + 4 MFMA (2048 FLOP each)
// -> auxiliary instr per FLOP ~30x below the scalar core (r11: 73% VALU busy
// on fma+cvt issue). Scalar fallback if probe failed. (256,2): 128-VGPR cap.
// ---------------------------------------------------------------------------
__launch_bounds__(256, 2)
__global__ void gemm_fx64(GemmP p) {
  constexpr int TS = 64, KS = 32, PAD = 68, TPR = 4, EPT = 8;
  __shared__ __align__(16) float As[KS][PAD];
  __shared__ __align__(16) float Bs[KS][PAD];
  int dyn = p.dflag[0];
  int ok = g_tab[516];
  int bz = blockIdx.z;
  int gx = gridDim.x;
  int nwg = gx * gridDim.y;
  int lin = blockIdx.y * gx + blockIdx.x;
  int q = nwg >> 3, r = nwg & 7;
  int xcd = lin & 7, cidx = lin >> 3;
  int nl = (xcd < r ? xcd * (q + 1) : r * (q + 1) + (xcd - r) * q) + cidx;
  int by = nl / gx;
  int row0 = by * TS, col0 = (nl - by * gx) * TS;
  int t = threadIdx.x;
  // MFMA mapping
  int lane = t & 63, wv = t >> 6;
  int ln = lane & 15, kg = lane >> 4;
  int wm = (wv >> 1) << 5, wn = (wv & 1) << 5;
  int myinv = g_tab[512 + kg];
  // scalar-fallback mapping
  int rg = t >> 4, cg = t & 15;

  f64x4 acc0, acc1, acc2, acc3;  // MFMA quadrant accs; fallback reuses as acc[4][4]
#pragma unroll
  for (int v = 0; v < 4; v++) { acc0[v] = 0.0; acc1[v] = 0.0; acc2[v] = 0.0; acc3[v] = 0.0; }
  unsigned apf[EPT], bpf[EPT];

  for (int seg = 0; seg < 2; seg++) {
    const void* Ap; const void* Bp;
    long long aofs, bofs;
    int lda, ldb, tA, tB, K, adin, bdin;
    if (seg == 0) {
      Ap = p.A; aofs = p.aoff + (long long)bz * p.sA; lda = p.lda; tA = p.tA; adin = p.adin;
      Bp = p.B; bofs = p.boff + (long long)bz * p.sB; ldb = p.ldb; tB = p.tB; bdin = p.bdin;
      K = p.K;
    } else {
      if (!p.A2) break;
      Ap = p.A2; aofs = 0; lda = p.lda2; tA = 0; adin = 0;
      Bp = p.B2; bofs = p.b2off; ldb = p.ldb2; tB = 0; bdin = p.b2din;
      K = p.K2;
    }
    int a_loc = tA ? (t % TS) : (t / TPR);
    int a_k0  = tA ? (t / TS) : (t % TPR);
    int am = row0 + a_loc;
    bool a_okb = am < p.M;
    int b_loc = tB ? (t / TPR) : (t % TS);
    int b_k0  = tB ? (t % TPR) : (t / TS);
    int bn = col0 + b_loc;
    bool b_okb = bn < p.Nc;
    long long abase = aofs + (tA ? (long long)a_k0 * lda + am : (long long)am * lda + a_k0);
    long long austr = tA ? (long long)TPR * lda : TPR;
    long long astep = tA ? (long long)KS * lda : KS;
    long long bbase = bofs + (tB ? (long long)bn * ldb + b_k0 : (long long)b_k0 * ldb + bn);
    long long bustr = tB ? TPR : (long long)TPR * ldb;
    long long bstep = tB ? KS : (long long)KS * ldb;

    auto LOAD = [&](int k0) {
#pragma unroll
      for (int u = 0; u < EPT; u++) {
        int k = k0 + a_k0 + u * TPR;
        apf[u] = (a_okb && k < K) ? ldbits(Ap, abase + u * austr, dyn, adin) : 0u;
      }
#pragma unroll
      for (int u = 0; u < EPT; u++) {
        int k = k0 + b_k0 + u * TPR;
        bpf[u] = (b_okb && k < K) ? ldbits(Bp, bbase + u * bustr, dyn, bdin) : 0u;
      }
      abase += astep; bbase += bstep;
    };
    auto STORE = [&]() {
#pragma unroll
      for (int u = 0; u < EPT; u++) As[a_k0 + u * TPR][a_loc] = __uint_as_float(apf[u]);
#pragma unroll
      for (int u = 0; u < EPT; u++) Bs[b_k0 + u * TPR][b_loc] = __uint_as_float(bpf[u]);  // unpermuted
    };
    int nst = (K + KS - 1) / KS;
    LOAD(0);
    for (int ts = 0; ts < nst; ts++) {
      __syncthreads();
      STORE();
      __syncthreads();
      if (ts + 1 < nst) LOAD((ts + 1) * KS);
      if (ok) {
#pragma unroll
        for (int g4 = 0; g4 < KS / 4; g4++) {
          int kb = g4 << 2;
          double a0 = (double)As[kb + kg][wm + ln];
          double a1 = (double)As[kb + kg][wm + 16 + ln];
          double b0 = (double)Bs[kb + myinv][wn + ln];
          double b1 = (double)Bs[kb + myinv][wn + 16 + ln];
          acc0 = __builtin_amdgcn_mfma_f64_16x16x4f64(a0, b0, acc0, 0, 0, 0);
          acc1 = __builtin_amdgcn_mfma_f64_16x16x4f64(a0, b1, acc1, 0, 0, 0);
          acc2 = __builtin_amdgcn_mfma_f64_16x16x4f64(a1, b0, acc2, 0, 0, 0);
          acc3 = __builtin_amdgcn_mfma_f64_16x16x4f64(a1, b1, acc3, 0, 0, 0);
        }
      } else {
        // scalar fallback (acc0..3 as acc[i][j], i = 2*(reg>>1)? use flat map)
#pragma unroll
        for (int kk = 0; kk < KS; kk++) {
          double av[4], bv[4];
#pragma unroll
          for (int i = 0; i < 4; i++) av[i] = (double)As[kk][4 * rg + i];
#pragma unroll
          for (int j = 0; j < 4; j++) bv[j] = (double)Bs[kk][cg + 16 * j];
#pragma unroll
          for (int j = 0; j < 4; j++) {
            acc0[j] = fma(av[0], bv[j], acc0[j]);
            acc1[j] = fma(av[1], bv[j], acc1[j]);
            acc2[j] = fma(av[2], bv[j], acc2[j]);
            acc3[j] = fma(av[3], bv[j], acc3[j]);
          }
        }
      }
    }
  }
  const float* addb = p.add;
  float* Cb = p.C + (long long)bz * p.sC;
  if (ok) {
    int rtv[4], ctv[4];
#pragma unroll
    for (int v = 0; v < 4; v++) {
      rtv[v] = g_tab[lane * 4 + v];
      ctv[v] = g_tab[256 + lane * 4 + v];
    }
#pragma unroll
    for (int rr = 0; rr < 2; rr++) {
#pragma unroll
      for (int cc = 0; cc < 2; cc++) {
#pragma unroll
        for (int v = 0; v < 4; v++) {
          int m = row0 + wm + rr * 16 + rtv[v];
          int n = col0 + wn + cc * 16 + ctv[v];
          if (m >= p.M || n >= p.Nc) continue;
          double val = (rr == 0 ? (cc == 0 ? acc0[v] : acc1[v])
                               : (cc == 0 ? acc2[v] : acc3[v])) * p.scale;
          if (p.bias)
            val += dyn ? (double)bf2f(((const unsigned short*)p.bias)[n])
                       : (double)((const float*)p.bias)[n];
          if (addb) val += (double)addb[(long long)m * p.ldadd + n];
          if (p.relu) val = fmax(val, 0.0);
          Cb[(long long)m * p.ldc + n] = (float)val;
        }
      }
    }
  } else {
#pragma unroll
    for (int i = 0; i < 4; i++) {
      int m = row0 + 4 * rg + i;
      if (m >= p.M) continue;
#pragma unroll
      for (int j = 0; j < 4; j++) {
        int n = col0 + cg + 16 * j;
        if (n >= p.Nc) continue;
        double v = (i == 0 ? acc0[j] : i == 1 ? acc1[j] : i == 2 ? acc2[j] : acc3[j]) * p.scale;
        if (p.bias)
          v += dyn ? (double)bf2f(((const unsigned short*)p.bias)[n])
                   : (double)((const float*)p.bias)[n];
        if (addb) v += (double)addb[(long long)m * p.ldadd + n];
        if (p.relu) v = fmax(v, 0.0);
        Cb[(long long)m * p.ldc + n] = (float)v;
      }
    }
  }
}

// ---------------------------------------------------------------------------
// Row softmax in-place: f32 storage, f64 internal
// ---------------------------------------------------------------------------
__launch_bounds__(256)
__global__ void row_softmax_k(float* __restrict__ A, int N) {
  long long row = (long long)blockIdx.x * 4 + (threadIdx.x >> 6);
  int lane = threadIdx.x & 63;
  float* a = A + row * N;
  double ev[8];
  int nc = N >> 6;
  double mx = -INFINITY;
  for (int k = 0; k < nc; k++) mx = fmax(mx, (double)a[lane + (k << 6)]);
  for (int off = 32; off; off >>= 1) mx = fmax(mx, __shfl_xor(mx, off, 64));
  double s = 0.0;
  for (int k = 0; k < nc; k++) { double e = exp((double)a[lane + (k << 6)] - mx); ev[k] = e; s += e; }
  for (int off = 32; off; off >>= 1) s += __shfl_xor(s, off, 64);
  double inv = 1.0 / s;
  for (int k = 0; k < nc; k++) a[lane + (k << 6)] = (float)(ev[k] * inv);
}

// ---------------------------------------------------------------------------
// Ms = 0.5*(Aff + Aff^T) -> f32
// ---------------------------------------------------------------------------
__launch_bounds__(256)
__global__ void msym_k(const void* __restrict__ Aff, float* __restrict__ Ms, int d,
                       const int* __restrict__ dflag) {
  int fl = dflag[0];
  int idx = blockIdx.x * 256 + threadIdx.x;
  if (idx < d * d) {
    int i = idx / d, j = idx - i * d;
    double a, b;
    if (fl) {
      a = (double)bf2f(((const unsigned short*)Aff)[idx]);
      b = (double)bf2f(((const unsigned short*)Aff)[j * d + i]);
    } else {
      a = (double)((const float*)Aff)[idx];
      b = (double)((const float*)Aff)[j * d + i];
    }
    Ms[idx] = (float)(0.5 * (a + b));
  }
}

// ---------------------------------------------------------------------------
// Sinkhorn (padded RPM), log-domain fixed point: S f32, u/v f64, P f32.
// ---------------------------------------------------------------------------
__launch_bounds__(256)
__global__ void sink_u_k(const float* __restrict__ S, const double* __restrict__ V,
                         double* __restrict__ U, int N) {
  extern __shared__ double vsh[];
  int b = blockIdx.y;
  const float* Sb = S + (long long)b * N * N;
  const double* Vb = V + (long long)b * N;
  int tid = threadIdx.x, lane = tid & 63, wv = tid >> 6;
  for (int c = tid; c < N; c += 256) vsh[c] = Vb[c];
  __syncthreads();
  int row = blockIdx.x * 4 + wv;
  const float* Sr = Sb + (long long)row * N;
  double m = (lane == 0) ? 0.0 : -INFINITY;
  double s = (lane == 0) ? 1.0 : 0.0;
  for (int c = lane; c < N; c += 64) {
    double x = (double)Sr[c] - vsh[c];
    if (x > m) { s = s * exp(m - x) + 1.0; m = x; }
    else s += exp(x - m);
  }
  for (int off = 32; off; off >>= 1) {
    double mo = __shfl_xor(m, off, 64);
    double so = __shfl_xor(s, off, 64);
    double mm = fmax(m, mo);
    s = s * exp(m - mm) + so * exp(mo - mm);
    m = mm;
  }
  if (lane == 0) U[(long long)b * N + row] = m + log(s);
}

// 16 columns x 16 row-groups per block: grid (N/16, pc)
__launch_bounds__(256)
__global__ void sink_v_k(const float* __restrict__ S, const double* __restrict__ U,
                         double* __restrict__ V, int N) {
  extern __shared__ double ush[];
  double* mred = ush + N;
  double* sred = mred + 256;
  int b = blockIdx.y;
  const float* Sb = S + (long long)b * N * N;
  int tid = threadIdx.x, cl = tid & 15, rg = tid >> 4;
  int c = blockIdx.x * 16 + cl;
  for (int i = tid; i < N; i += 256) ush[i] = U[(long long)b * N + i];
  __syncthreads();
  double m = (rg == 0) ? 0.0 : -INFINITY;
  double s = (rg == 0) ? 1.0 : 0.0;
  for (int i = rg; i < N; i += 16) {
    double x = (double)Sb[(long long)i * N + c] - ush[i];
    if (x > m) { s = s * exp(m - x) + 1.0; m = x; }
    else s += exp(x - m);
  }
  mred[rg * 16 + cl] = m; sred[rg * 16 + cl] = s;
  __syncthreads();
  if (rg == 0) {
    for (int g = 1; g < 16; g++) {
      double mo = mred[g * 16 + cl], so = sred[g * 16 + cl];
      double mm = fmax(m, mo);
      s = s * exp(m - mm) + so * exp(mo - mm);
      m = mm;
    }
    V[(long long)b * N + c] = m + log(s);
  }
}

__launch_bounds__(256)
__global__ void sink_p_k(const float* __restrict__ S, const double* __restrict__ U,
                         const double* __restrict__ V, float* __restrict__ P, int N) {
  int b = blockIdx.y;
  long long base = (long long)b * N * N;
  const double* Ub = U + (long long)b * N;
  const double* Vb = V + (long long)b * N;
  for (long long e = (long long)blockIdx.x * 256 + threadIdx.x; e < (long long)N * N;
       e += (long long)gridDim.x * 256) {
    int i = (int)(e / N), j = (int)(e - (long long)i * N);
    P[base + e] = (float)exp((double)S[base + e] - Ub[i] - Vb[j]);
  }
}

// ---------------------------------------------------------------------------
// Top-k pooling: f64 math on f32-stored emb; FINAL SCORE ROUNDED TO F32
// ---------------------------------------------------------------------------
__launch_bounds__(256)
__global__ void colstats_k(const float* __restrict__ emb, double* __restrict__ stats, int N, int d) {
  int g = blockIdx.y;
  int cl = threadIdx.x & 63;
  int c = blockIdx.x * 64 + cl;
  int rg = threadIdx.x >> 6;
  const float* e = emb + (long long)g * N * d;
  __shared__ double redm[4][64];
  __shared__ double reds[4][64];
  double mx = -INFINITY;
  for (int r = rg; r < N; r += 4) mx = fmax(mx, (double)e[(long long)r * d + c]);
  redm[rg][cl] = mx;
  __syncthreads();
  mx = fmax(fmax(redm[0][cl], redm[1][cl]), fmax(redm[2][cl], redm[3][cl]));
  __syncthreads();
  double s = 0.0;
  for (int r = rg; r < N; r += 4) s += exp((double)e[(long long)r * d + c] - mx);
  reds[rg][cl] = s;
  __syncthreads();
  if (rg == 0) {
    s = reds[0][cl] + reds[1][cl] + reds[2][cl] + reds[3][cl];
    stats[((long long)g * d + c) * 2] = mx;
    stats[((long long)g * d + c) * 2 + 1] = 1.0 / s;
  }
}

__launch_bounds__(256)
__global__ void score_k(const float* __restrict__ emb, const double* __restrict__ stats,
                        double* __restrict__ score, int N, int d) {
  int g = blockIdx.y;
  int r = blockIdx.x * 64 + (threadIdx.x >> 2);
  int sub = threadIdx.x & 3;
  const float* e = emb + ((long long)g * N + r) * d;
  const double* st = stats + (long long)g * d * 2;
  double s = 0.0;
  for (int c = sub; c < d; c += 4) s += exp((double)e[c] - st[2 * c]) * st[2 * c + 1];
  s += __shfl_down(s, 2, 4);
  s += __shfl_down(s, 1, 4);
  if (sub == 0) score[(long long)g * N + r] = (double)(float)s;
}

__launch_bounds__(256)
__global__ void topk_sort_k(const double* __restrict__ score, int* __restrict__ SIDX,
                            int N, int k) {
  __shared__ double sv[1024];
  __shared__ int si[1024];
  int g = blockIdx.x, tid = threadIdx.x;
  (void)k;
  for (int i = tid; i < N; i += 256) { sv[i] = score[(long long)g * N + i]; si[i] = i; }
  __syncthreads();
  for (int kk = 2; kk <= N; kk <<= 1) {
    for (int j = kk >> 1; j > 0; j >>= 1) {
      for (int i = tid; i < N; i += 256) {
        int ixj = i ^ j;
        if (ixj > i) {
          double v1 = sv[i], v2 = sv[ixj];
          int x1 = si[i], x2 = si[ixj];
          bool gtr = (v1 < v2) || (v1 == v2 && x1 > x2);
          bool up = ((i & kk) == 0);
          if (gtr == up) { sv[i] = v2; sv[ixj] = v1; si[i] = x2; si[ixj] = x1; }
        }
      }
      __syncthreads();
    }
  }
  for (int i = tid; i < N; i += 256) SIDX[(long long)g * N + i] = si[i];
}

// grid-stride gather over (chunk, g)
__launch_bounds__(256)
__global__ void gather_k(const int* __restrict__ SIDX, const float* __restrict__ emb,
                         float* __restrict__ out, int N, int d, int k) {
  int g = blockIdx.y;
  int total = k * d;
  const int* sx = SIDX + (long long)g * N;
  const float* eb = emb + (long long)g * N * d;
  float* ob = out + (long long)g * total;
  int stride = gridDim.x * 256;
  int e0 = blockIdx.x * 256 + threadIdx.x;
  int r = e0 / d, c = e0 - r * d;
  int rs = stride / d, cs = stride - rs * d;
  for (int e = e0; e < total; e += stride) {
    ob[e] = eb[(long long)sx[r] * d + c];
    r += rs; c += cs;
    if (c >= d) { c -= d; r += 1; }
  }
}

// output converter: f32 -> bf16/f32 per flag
__launch_bounds__(256)
__global__ void cvt_out_k(const float* __restrict__ src, void* __restrict__ dst,
                          long long oofs, int n, const int* __restrict__ dflag) {
  int fl = dflag[0];
  int i = blockIdx.x * 256 + threadIdx.x;
  if (i < n) {
    float v = src[i];
    if (fl) ((__hip_bfloat16*)dst)[oofs + i] = __float2bfloat16(v);
    else ((float*)dst)[oofs + i] = v;
  }
}

// ---------------------------------------------------------------------------
// Host orchestration — f32 arena, ws_size-adaptive pair batching.
// ---------------------------------------------------------------------------
extern "C" void kernel_launch(void* const* d_in, const int* in_sizes, int n_in,
                              void* d_out, int out_size, void* d_ws, size_t ws_size,
                              hipStream_t stream) {
  (void)in_sizes; (void)n_in; (void)out_size;
  static const int NL[3] = {1024, 512, 256};
  static const int DL[3] = {512, 256, 128};
  static const int DINL[3] = {3, 512, 256};
  static const int IWp[3]={0,11,23}, IBp[3]={1,12,24}, IWe[3]={2,13,25}, IBe[3]={3,14,26};
  static const int IWt[3]={-1,15,27};
  static const int IWa[3]={4,16,28}, IBa[3]={5,17,29}, IWu[3]={6,18,30}, IBu[3]={7,19,31};
  static const int IAff[3]={8,20,32}, IWc[3]={9,21,33}, IBc[3]={10,22,34};

  auto Wv = [&](int t) { return (const void*)d_in[4 + t]; };

  float* ws = (float*)d_ws;
  const long long PER_PC = 5257232LL;  // floats per pair
  int pc = 1;
  if (ws_size >= (size_t)(PER_PC * 4 * 4 + 64)) pc = 4;
  else if (ws_size >= (size_t)(PER_PC * 2 * 4 + 64)) pc = 2;

  float* A0 = ws;
  float* B0 = A0 + 2097152LL * pc;
  float* C0 = B0 + 1048576LL * pc;
  float* D0 = C0 + 1048576LL * pc;
  float* IN = D0 + 524288LL * pc;
  double* ST = (double*)(IN + 524288LL * pc);
  double* SC = ST + 2048LL * pc;
  double* SU = SC + 2048LL * pc;
  double* SV = SU + 1024LL * pc;
  int* SIDX = (int*)(SV + 1024LL * pc);
  int* FLAG = SIDX + 2048LL * pc;

  mfma_probe_k<<<dim3(1), dim3(64), 0, stream>>>();
  detect_dtype_k<<<dim3(1), dim3(64), 0, stream>>>((const unsigned short*)d_in[0], FLAG);

  GemmP p_;
  auto gemm = [&](const void* A, long long aoff, long long sA, int lda, int tA, int adin,
                  const void* B, long long boff, long long sB, int ldb, int tB, int bdin,
                  const float* A2, int lda2,
                  const void* B2, long long b2off, int ldb2, int K2, int b2din,
                  const void* bias, const float* add, int ldadd,
                  float* C, long long sC, int ldc, int M, int Nc, int K,
                  double scale, int relu, int batches) {
    p_.dflag = FLAG;
    p_.A = A; p_.aoff = aoff; p_.sA = sA; p_.lda = lda; p_.tA = tA; p_.adin = adin;
    p_.B = B; p_.boff = boff; p_.sB = sB; p_.ldb = ldb; p_.tB = tB; p_.bdin = bdin;
    p_.A2 = A2; p_.lda2 = lda2;
    p_.B2 = B2; p_.b2off = b2off; p_.ldb2 = ldb2; p_.K2 = K2; p_.b2din = b2din;
    p_.bias = bias; p_.add = add; p_.ldadd = ldadd;
    p_.C = C; p_.sC = sC; p_.ldc = ldc; p_.M = M; p_.Nc = Nc; p_.K = K;
    p_.scale = scale; p_.relu = relu;
    long long b64 = (long long)((Nc + 63) / 64) * ((M + 63) / 64) * batches;
    if (b64 >= 384) {
      dim3 grid((Nc + 63) / 64, (M + 63) / 64, batches);
      gemm_fx64<<<grid, dim3(256), 0, stream>>>(p_);
    } else {
      dim3 grid((Nc + 31) / 32, (M + 31) / 32, batches);
      gemm_fx32<<<grid, dim3(256), 0, stream>>>(p_);
    }
  };

  for (int p0 = 0; p0 < 4; p0 += pc) {
    const int s = 2 * pc;
    for (int L = 0; L < 3; L++) {
      int N = NL[L], d = DL[L], din = DINL[L];
      long long ns = (long long)N * d, NN = (long long)N * N;
      int sN = s * N, pcN = pc * N;
      float* X2 = A0;
      float* H = B0;
      float* X3 = C0;
      float* Af = D0;
      float* Spt = A0;
      float* Ppt = A0 + (long long)pc * NN;
      float* G = B0;
      float* MSp = B0 + (long long)pc * ns;
      float* Y = B0;
      float* EMB = A0;

      if (L == 0) {
        long long poff = (long long)p0 * N * 3;
        float* X2t = X2 + (long long)pcN * 2 * d;
        gemm(d_in[0],poff,0,3,0,1, Wv(IWp[0]),0,0,d,0,1, nullptr,0, nullptr,0,0,0,0,
             Wv(IBp[0]), nullptr,0, X2, 0, 2*d, pcN, d, 3, 1.0, 1, 1);
        gemm(d_in[0],poff,0,3,0,1, Wv(IWe[0]),0,0,d,0,1, nullptr,0, nullptr,0,0,0,0,
             Wv(IBe[0]), nullptr,0, X2 + d, 0, 2*d, pcN, d, 3, 1.0, 1, 1);
        gemm(d_in[1],poff,0,3,0,1, Wv(IWp[0]),0,0,d,0,1, nullptr,0, nullptr,0,0,0,0,
             Wv(IBp[0]), nullptr,0, X2t, 0, 2*d, pcN, d, 3, 1.0, 1, 1);
        gemm(d_in[1],poff,0,3,0,1, Wv(IWe[0]),0,0,d,0,1, nullptr,0, nullptr,0,0,0,0,
             Wv(IBe[0]), nullptr,0, X2t + d, 0, 2*d, pcN, d, 3, 1.0, 1, 1);
      } else {
        gemm(IN,0,0,din,0,0, Wv(IWp[L]),0,0,d,0,1, nullptr,0, nullptr,0,0,0,0,
             Wv(IBp[L]), nullptr,0, X2, 0, 2*d, sN, d, din, 1.0, 1, 1);
        gemm(IN,0,0,din,0,0, Wv(IWe[L]),0,0,d,0,1, nullptr,0, nullptr,0,0,0,0,
             Wv(IBe[L]), nullptr,0, X2 + d, 0, 2*d, sN, d, din, 1.0, 1, 1);
      }
      if (L > 0) {
        float* SE = B0;
        double inv = (double)(float)(1.0 / sqrt((double)d));  // np.float32 constant
        gemm(X2,0,0,2*d,0,0, Wv(IWt[L]),0,0,d,0,1, nullptr,0, nullptr,0,0,0,0,
             nullptr, nullptr,0, SE, 0, d, sN, d, 2*d, 1.0, 0, 1);
        gemm(SE,0,ns,d,0,0, SE,0,ns,d,1,0, nullptr,0, nullptr,0,0,0,0,
             nullptr, nullptr,0, Af, NN, N, N, N, d, inv, 0, s);
        row_softmax_k<<<dim3(sN / 4), dim3(256), 0, stream>>>(Af, N);
      }
      gemm(X2,0,0,2*d,0,0, Wv(IWa[L]),0,0,d,0,1, nullptr,0, nullptr,0,0,0,0,
           Wv(IBa[L]), nullptr,0, H, 0, d, sN, d, 2*d, 1.0, 0, 1);
      if (L == 0) {
        gemm(d_in[2],(long long)p0*NN,NN,N,0,1, H,0,ns,d,0,0, nullptr,0, nullptr,0,0,0,0,
             nullptr, nullptr,0, X3, ns, d, N, d, N, 1.0, 0, pc);
        gemm(d_in[3],(long long)p0*NN,NN,N,0,1, H + (long long)pc*ns,0,ns,d,0,0, nullptr,0, nullptr,0,0,0,0,
             nullptr, nullptr,0, X3 + (long long)pc*ns, ns, d, N, d, N, 1.0, 0, pc);
      } else {
        gemm(Af,0,NN,N,0,0, H,0,ns,d,0,0, nullptr,0, nullptr,0,0,0,0,
             nullptr, nullptr,0, X3, ns, d, N, d, N, 1.0, 0, s);
      }
      gemm(X2,0,0,2*d,0,0, Wv(IWu[L]),0,0,d,0,1, nullptr,0, nullptr,0,0,0,0,
           Wv(IBu[L]), X3,d, X3, 0, d, sN, d, 2*d, 1.0, 1, 1);
      msym_k<<<dim3((d * d + 255) / 256), dim3(256), 0, stream>>>(Wv(IAff[L]), MSp, d, FLAG);
      gemm(X3 + (long long)pc*ns,0,0,d,0,0, MSp,0,0,d,0,0, nullptr,0, nullptr,0,0,0,0,
           nullptr, nullptr,0, G, 0, d, pcN, d, d, 1.0, 0, 1);
      gemm(X3,0,ns,d,0,0, G,0,ns,d,1,0, nullptr,0, nullptr,0,0,0,0,
           nullptr, nullptr,0, Spt, NN, N, N, N, d, 1.0, 0, pc);
      hipMemsetAsync(SV, 0, (size_t)pc * N * sizeof(double), stream);
      for (int it = 0; it < 20; it++) {
        sink_u_k<<<dim3(N / 4, pc), dim3(256), N * sizeof(double), stream>>>(Spt, SV, SU, N);
        sink_v_k<<<dim3(N / 16, pc), dim3(256), (N + 512) * sizeof(double), stream>>>(Spt, SU, SV, N);
      }
      sink_p_k<<<dim3(256, pc), dim3(256), 0, stream>>>(Spt, SU, SV, Ppt, N);
      if (L == 2) {
        int on = pc * 65536;
        cvt_out_k<<<dim3((on + 255) / 256), dim3(256), 0, stream>>>(
            Ppt, d_out, (long long)p0 * 65536, on, FLAG);
      } else {
        gemm(Ppt,0,NN,N,0,0, X3 + (long long)pc*ns,0,ns,d,0,0, nullptr,0, nullptr,0,0,0,0,
             nullptr, nullptr,0, Y, ns, d, N, d, N, 1.0, 0, pc);
        gemm(Ppt,0,NN,N,1,0, X3,0,ns,d,0,0, nullptr,0, nullptr,0,0,0,0,
             nullptr, nullptr,0, Y + (long long)pc*ns, ns, d, N, d, N, 1.0, 0, pc);
        gemm(X3,0,0,d,0,0, Wv(IWc[L]),0,0,d,0,1, Y,d, Wv(IWc[L]),(long long)d*d,d,d,1,
             Wv(IBc[L]), nullptr,0, EMB, 0, d, sN, d, d, 1.0, 0, 1);
        colstats_k<<<dim3(d / 64, s), dim3(256), 0, stream>>>(EMB, ST, N, d);
        score_k<<<dim3(N / 64, s), dim3(256), 0, stream>>>(EMB, ST, SC, N, d);
        topk_sort_k<<<dim3(s), dim3(256), 0, stream>>>(SC, SIDX, N, N / 2);
        gather_k<<<dim3(128, s), dim3(256), 0, stream>>>(SIDX, EMB, IN, N, d, N / 2);
      }
    }
  }
}